// Round 1
// baseline (332.993 us; speedup 1.0000x reference)
//
#include <hip/hip_runtime.h>

#define NBATCH 64
#define LLEN   64
#define HDIM   128
#define NSTEP  64
#define NIN    16
#define HISTP  136   // padded stride for c-history (bank-conflict-free, 16B aligned)

__device__ __forceinline__ float sigf(float x) { return 1.f / (1.f + __expf(-x)); }

__global__ __launch_bounds__(256) void copy_trip_k(const float4* __restrict__ src,
                                                   float4* __restrict__ dst) {
    int i = blockIdx.x * 256 + threadIdx.x;   // 65536 float4 total
    dst[i] = src[i];
}

__global__ __launch_bounds__(512, 1) void recur_k(
    const float* __restrict__ emb, const float* __restrict__ Wg,
    const float* __restrict__ bg,  const float* __restrict__ Wl,
    const float* __restrict__ bl,  float* __restrict__ out) {
    __shared__ float inp_s[256];            // [c(128) | h(128)]
    __shared__ float g_s[512];
    __shared__ float hist[NSTEP * HISTP];   // c_s history, padded stride
    __shared__ float Wl_s[HDIM * NIN];      // 8 KB
    __shared__ float proj_s[NSTEP * NIN];   // 4 KB

    const int b = blockIdx.x, t = threadIdx.x;

    for (int i = t; i < HDIM * NIN; i += 512) Wl_s[i] = Wl[i];
    if (t < HDIM)       inp_s[t] = emb[b * (LLEN * HDIM) + t];  // embedding[b,0,:]
    else if (t < 256)   inp_s[t] = 0.f;                          // h0 = 0
    const float bgj = bg[t];
    const float* wcol = Wg + t;  // column j = t of [256,512] row-major
    __syncthreads();

    for (int s = 0; s < NSTEP; ++s) {
        // ---- gates: g_j = b_g[j] + sum_k inp[k] * W[k][j] ----
        float g = bgj;
        const float4* inp4 = (const float4*)inp_s;
        #pragma unroll 16
        for (int k4 = 0; k4 < 64; ++k4) {
            float4 v = inp4[k4];   // uniform address -> LDS broadcast
            int k = k4 * 4;
            g = fmaf(v.x, wcol[(k + 0) * 512], g);
            g = fmaf(v.y, wcol[(k + 1) * 512], g);
            g = fmaf(v.z, wcol[(k + 2) * 512], g);
            g = fmaf(v.w, wcol[(k + 3) * 512], g);
        }
        g_s[t] = g;
        __syncthreads();
        // ---- state update (threads 0..127 own h index) ----
        if (t < HDIM) {
            float fg = sigf(g_s[t]);
            float ig = sigf(g_s[HDIM + t]);
            float og = sigf(g_s[2 * HDIM + t]);
            float cd = tanhf(g_s[3 * HDIM + t]);
            float c_old = (s == 0) ? 0.f : inp_s[t];   // c0 = 0 at step 0
            float c_new = fg * c_old + ig * cd;
            float h_new = og * tanhf(c_new);
            inp_s[t] = c_new;
            inp_s[HDIM + t] = h_new;
            hist[s * HISTP + t] = c_new;
        }
        __syncthreads();
    }

    // ---- projection: 1024 (s,i) pairs, 2 per thread ----
    #pragma unroll
    for (int r = 0; r < 2; ++r) {
        int p = t * 2 + r;           // 0..1023
        int s = p >> 4, i = p & 15;
        float acc = bl[i];
        const float4* c4 = (const float4*)&hist[s * HISTP];
        #pragma unroll 8
        for (int h4 = 0; h4 < HDIM / 4; ++h4) {
            float4 cv = c4[h4];
            int h = h4 * 4;
            acc = fmaf(cv.x, Wl_s[(h + 0) * NIN + i], acc);
            acc = fmaf(cv.y, Wl_s[(h + 1) * NIN + i], acc);
            acc = fmaf(cv.z, Wl_s[(h + 2) * NIN + i], acc);
            acc = fmaf(cv.w, Wl_s[(h + 3) * NIN + i], acc);
        }
        proj_s[s * NIN + i] = acc;
    }
    __syncthreads();

    // ---- write out: rows s*64+l all share proj_s[s] ; 16384 float4 per block ----
    float4* ob = (float4*)(out + (size_t)b * (NSTEP * LLEN * NIN));
    const float4* pj = (const float4*)proj_s;
    for (int u = t; u < NSTEP * LLEN * NIN / 4; u += 512) {
        int row = u >> 2;            // 0..4095  (= s*64 + l)
        int s = row >> 6;
        int ib = u & 3;
        ob[u] = pj[s * 4 + ib];
    }
}

extern "C" void kernel_launch(void* const* d_in, const int* in_sizes, int n_in,
                              void* d_out, int out_size, void* d_ws, size_t ws_size,
                              hipStream_t stream) {
    const float* trip = (const float*)d_in[0];
    // d_in[1] = valid_len : unused by the reference computation
    const float* emb  = (const float*)d_in[2];
    const float* Wg   = (const float*)d_in[3];
    const float* bgp  = (const float*)d_in[4];
    const float* Wlp  = (const float*)d_in[5];
    const float* blp  = (const float*)d_in[6];
    float* out = (float*)d_out;

    // output = [trip (64*256*16=262144 floats) | out (64*4096*16=4194304 floats)]
    copy_trip_k<<<256, 256, 0, stream>>>((const float4*)trip, (float4*)out);
    recur_k<<<NBATCH, 512, 0, stream>>>(emb, Wg, bgp, Wlp, blp, out + 262144);
}

// Round 2
// 190.943 us; speedup vs baseline: 1.7439x; 1.7439x over previous
//
#include <hip/hip_runtime.h>

#define NBATCH 64
#define LLEN   64
#define HDIM   128
#define NSTEP  64
#define NIN    16
#define HISTP  132    // hist stride: 132*4B=528B, 16B-aligned, breaks 128-stride banks
#define NREG   208    // W rows held in registers per thread
#define NCHUNK 3      // 3 chunks x 16 rows streamed from L2 per step (rows 208..255)

__device__ __forceinline__ float sigf(float x) { return 1.f / (1.f + __expf(-x)); }

__global__ __launch_bounds__(256) void copy_trip_k(const float4* __restrict__ src,
                                                   float4* __restrict__ dst) {
    int i = blockIdx.x * 256 + threadIdx.x;   // 65536 float4 total
    dst[i] = src[i];
}

__global__ __launch_bounds__(512, 2) void recur_k(
    const float* __restrict__ emb, const float* __restrict__ Wg,
    const float* __restrict__ bg,  const float* __restrict__ Wl,
    const float* __restrict__ bl,  float* __restrict__ out) {
    __shared__ float inp_s[256];            // [c(128) | h(128)] (step0: emb | 0)
    __shared__ float g_s[512];
    __shared__ float hist[NSTEP * HISTP];   // c_s history
    __shared__ float Wl_s[HDIM * NIN];      // 8 KB
    __shared__ float proj_s[NSTEP * NIN];   // 4 KB

    const int b = blockIdx.x, t = threadIdx.x;
    const int lane = t & 63;

    // ---- W column j = t, rows 0..NREG-1 -> registers (one-time, L2/L3-hot) ----
    float Wr[NREG];
    #pragma unroll
    for (int k = 0; k < NREG; ++k) Wr[k] = Wg[k * 512 + t];

    for (int i = t; i < HDIM * NIN; i += 512) Wl_s[i] = Wl[i];
    if (t < HDIM)       inp_s[t] = emb[b * (LLEN * HDIM) + t];  // embedding[b,0,:]
    else if (t < 256)   inp_s[t] = 0.f;                          // h0 = 0
    const float bgj = bg[t];
    const float* wtail = Wg + NREG * 512 + t;
    __syncthreads();

    for (int s = 0; s < NSTEP; ++s) {
        // one ds_read_b128 per lane: lane holds inp[4*lane .. 4*lane+3]
        int4 v = *(const int4*)&inp_s[lane * 4];

        float a0 = bgj, a1 = 0.f;
        // ---- register-resident part: k = 0..NREG-1, broadcast via v_readlane ----
        #pragma unroll
        for (int l = 0; l < NREG / 4; ++l) {
            int k = l * 4;
            float s0 = __int_as_float(__builtin_amdgcn_readlane(v.x, l));
            float s1 = __int_as_float(__builtin_amdgcn_readlane(v.y, l));
            float s2 = __int_as_float(__builtin_amdgcn_readlane(v.z, l));
            float s3 = __int_as_float(__builtin_amdgcn_readlane(v.w, l));
            a0 = fmaf(s0, Wr[k + 0], a0);
            a1 = fmaf(s1, Wr[k + 1], a1);
            a0 = fmaf(s2, Wr[k + 2], a0);
            a1 = fmaf(s3, Wr[k + 3], a1);
        }
        // ---- streamed tail: rows NREG..255 from L2, 16 regs live at a time ----
        {
            const float* wt = wtail;
            asm volatile("" : "+v"(wt));   // defeat LICM: keep these loads per-step
            #pragma unroll
            for (int c = 0; c < NCHUNK; ++c) {
                float Ws[16];
                #pragma unroll
                for (int i = 0; i < 16; ++i) Ws[i] = wt[(c * 16 + i) * 512];
                #pragma unroll
                for (int q = 0; q < 4; ++q) {
                    int l = NREG / 4 + c * 4 + q;
                    float s0 = __int_as_float(__builtin_amdgcn_readlane(v.x, l));
                    float s1 = __int_as_float(__builtin_amdgcn_readlane(v.y, l));
                    float s2 = __int_as_float(__builtin_amdgcn_readlane(v.z, l));
                    float s3 = __int_as_float(__builtin_amdgcn_readlane(v.w, l));
                    a0 = fmaf(s0, Ws[q * 4 + 0], a0);
                    a1 = fmaf(s1, Ws[q * 4 + 1], a1);
                    a0 = fmaf(s2, Ws[q * 4 + 2], a0);
                    a1 = fmaf(s3, Ws[q * 4 + 3], a1);
                }
            }
        }
        g_s[t] = a0 + a1;
        __syncthreads();

        // ---- state update (threads 0..127 own h index) ----
        if (t < HDIM) {
            float fg = sigf(g_s[t]);
            float ig = sigf(g_s[HDIM + t]);
            float og = sigf(g_s[2 * HDIM + t]);
            float cd = tanhf(g_s[3 * HDIM + t]);
            float c_old = (s == 0) ? 0.f : inp_s[t];   // c0 = 0 at step 0
            float c_new = fg * c_old + ig * cd;
            float h_new = og * tanhf(c_new);
            inp_s[t] = c_new;
            inp_s[HDIM + t] = h_new;
            hist[s * HISTP + t] = c_new;
        }
        __syncthreads();
    }

    // ---- projection: 1024 (s,i) pairs, 2 per thread ----
    #pragma unroll
    for (int r = 0; r < 2; ++r) {
        int p = t * 2 + r;           // 0..1023
        int s = p >> 4, i = p & 15;
        float acc = bl[i];
        const float4* c4 = (const float4*)&hist[s * HISTP];
        #pragma unroll 8
        for (int h4 = 0; h4 < HDIM / 4; ++h4) {
            float4 cv = c4[h4];
            int h = h4 * 4;
            acc = fmaf(cv.x, Wl_s[(h + 0) * NIN + i], acc);
            acc = fmaf(cv.y, Wl_s[(h + 1) * NIN + i], acc);
            acc = fmaf(cv.z, Wl_s[(h + 2) * NIN + i], acc);
            acc = fmaf(cv.w, Wl_s[(h + 3) * NIN + i], acc);
        }
        proj_s[s * NIN + i] = acc;
    }
    __syncthreads();

    // ---- write out: rows s*64+l all share proj_s[s]; 16384 float4 per block ----
    float4* ob = (float4*)(out + (size_t)b * (NSTEP * LLEN * NIN));
    const float4* pj = (const float4*)proj_s;
    for (int u = t; u < NSTEP * LLEN * NIN / 4; u += 512) {
        int row = u >> 2;            // 0..4095  (= s*64 + l)
        int s = row >> 6;
        int ib = u & 3;
        ob[u] = pj[s * 4 + ib];
    }
}

extern "C" void kernel_launch(void* const* d_in, const int* in_sizes, int n_in,
                              void* d_out, int out_size, void* d_ws, size_t ws_size,
                              hipStream_t stream) {
    const float* trip = (const float*)d_in[0];
    // d_in[1] = valid_len : unused by the reference computation
    const float* emb  = (const float*)d_in[2];
    const float* Wg   = (const float*)d_in[3];
    const float* bgp  = (const float*)d_in[4];
    const float* Wlp  = (const float*)d_in[5];
    const float* blp  = (const float*)d_in[6];
    float* out = (float*)d_out;

    // output = [trip (64*256*16=262144 floats) | out (64*4096*16=4194304 floats)]
    copy_trip_k<<<256, 256, 0, stream>>>((const float4*)trip, (float4*)out);
    recur_k<<<NBATCH, 512, 0, stream>>>(emb, Wg, bgp, Wlp, blp, out + 262144);
}

// Round 3
// 90.664 us; speedup vs baseline: 3.6728x; 2.1061x over previous
//
#include <hip/hip_runtime.h>

typedef _Float16 half2_t __attribute__((ext_vector_type(2)));

#define NBATCH 64
#define LLEN   64
#define HDIM   128
#define NSTEP  64
#define NIN    16
#define HISTP  132    // hist stride: 132*4B=528B, 16B-aligned

__device__ __forceinline__ float sigf(float x) { return 1.f / (1.f + __expf(-x)); }

__device__ __forceinline__ unsigned int h2u(half2_t h) {
    union { half2_t h; unsigned int u; } x; x.h = h; return x.u;
}
__device__ __forceinline__ half2_t u2h(unsigned int u) {
    union { half2_t h; unsigned int u; } x; x.u = u; return x.h;
}

__global__ __launch_bounds__(256) void copy_trip_k(const float4* __restrict__ src,
                                                   float4* __restrict__ dst) {
    int i = blockIdx.x * 256 + threadIdx.x;   // 65536 float4 total
    dst[i] = src[i];
}

__global__ __launch_bounds__(512) void recur_k(
    const float* __restrict__ emb, const float* __restrict__ Wg,
    const float* __restrict__ bg,  const float* __restrict__ Wl,
    const float* __restrict__ bl,  float* __restrict__ out) {
    __shared__ __align__(16) unsigned int pack_s[2][128];  // f16-packed [c|h], dbuf
    __shared__ float g_s[512];
    __shared__ float hist[NSTEP * HISTP];   // c_s history (f32)
    __shared__ float Wl_s[HDIM * NIN];      // 8 KB
    __shared__ float proj_s[NSTEP * NIN];   // 4 KB

    const int b = blockIdx.x, t = threadIdx.x;

    // ---- W column j = t as 128 packed f16 pairs, register-resident ----
    unsigned int Whu[128];
    #pragma unroll
    for (int k = 0; k < 128; ++k) {
        float w0 = Wg[(2 * k + 0) * 512 + t];
        float w1 = Wg[(2 * k + 1) * 512 + t];
        half2_t hp = { (_Float16)w0, (_Float16)w1 };
        Whu[k] = h2u(hp);
    }
    #pragma unroll
    for (int k = 0; k < 128; ++k) asm volatile("" : "+v"(Whu[k]));  // pin: defeat remat

    for (int i = t; i < HDIM * NIN; i += 512) Wl_s[i] = Wl[i];

    // ---- initial packed state: [emb(128) | h0=0(128)] ----
    if (t < 64) {
        float e0 = emb[b * (LLEN * HDIM) + 2 * t + 0];
        float e1 = emb[b * (LLEN * HDIM) + 2 * t + 1];
        half2_t hp = { (_Float16)e0, (_Float16)e1 };
        pack_s[0][t] = h2u(hp);
    } else if (t < 128) {
        pack_s[0][t] = 0u;
    }
    float c_reg = 0.f;             // threads 0..127 own c[t]; c0 = 0
    const float bgj = bg[t];
    __syncthreads();

    for (int s = 0; s < NSTEP; ++s) {
        // ---- gates: g_j = b[j] + sum_k inp[k]*W[k][j], f16 dot2, K=256 ----
        const uint4* p4 = (const uint4*)pack_s[s & 1];  // uniform addr -> LDS broadcast
        float a0 = bgj, a1 = 0.f;
        #pragma unroll
        for (int q = 0; q < 32; ++q) {
            uint4 u = p4[q];
            a0 = __builtin_amdgcn_fdot2(u2h(u.x), u2h(Whu[4 * q + 0]), a0, false);
            a1 = __builtin_amdgcn_fdot2(u2h(u.y), u2h(Whu[4 * q + 1]), a1, false);
            a0 = __builtin_amdgcn_fdot2(u2h(u.z), u2h(Whu[4 * q + 2]), a0, false);
            a1 = __builtin_amdgcn_fdot2(u2h(u.w), u2h(Whu[4 * q + 3]), a1, false);
        }
        g_s[t] = a0 + a1;
        __syncthreads();

        // ---- state update: threads 0..127 own h index t ----
        if (t < HDIM) {
            float fg = sigf(g_s[t]);
            float ig = sigf(g_s[HDIM + t]);
            float og = sigf(g_s[2 * HDIM + t]);
            float cd = tanhf(g_s[3 * HDIM + t]);
            float c_new = fg * c_reg + ig * cd;
            float h_new = og * tanhf(c_new);
            c_reg = c_new;
            hist[s * HISTP + t] = c_new;
            // pack (pairs across adjacent threads, same wave)
            float c_o = __shfl_xor(c_new, 1);
            float h_o = __shfl_xor(h_new, 1);
            if ((t & 1) == 0) {
                half2_t cp = { (_Float16)c_new, (_Float16)c_o };
                half2_t hp = { (_Float16)h_new, (_Float16)h_o };
                int nb = (s + 1) & 1;
                pack_s[nb][(t >> 1)]      = h2u(cp);
                pack_s[nb][64 + (t >> 1)] = h2u(hp);
            }
        }
        __syncthreads();
    }

    // ---- projection: 1024 (s,i) pairs, 2 per thread ----
    #pragma unroll
    for (int r = 0; r < 2; ++r) {
        int p = t * 2 + r;           // 0..1023
        int s = p >> 4, i = p & 15;
        float acc = bl[i];
        const float4* c4 = (const float4*)&hist[s * HISTP];
        #pragma unroll 8
        for (int h4 = 0; h4 < HDIM / 4; ++h4) {
            float4 cv = c4[h4];
            int h = h4 * 4;
            acc = fmaf(cv.x, Wl_s[(h + 0) * NIN + i], acc);
            acc = fmaf(cv.y, Wl_s[(h + 1) * NIN + i], acc);
            acc = fmaf(cv.z, Wl_s[(h + 2) * NIN + i], acc);
            acc = fmaf(cv.w, Wl_s[(h + 3) * NIN + i], acc);
        }
        proj_s[s * NIN + i] = acc;
    }
    __syncthreads();

    // ---- write out: rows s*64+l all share proj_s[s]; 16384 float4 per block ----
    float4* ob = (float4*)(out + (size_t)b * (NSTEP * LLEN * NIN));
    const float4* pj = (const float4*)proj_s;
    for (int u = t; u < NSTEP * LLEN * NIN / 4; u += 512) {
        int row = u >> 2;            // 0..4095  (= s*64 + l)
        int s = row >> 6;
        int ib = u & 3;
        ob[u] = pj[s * 4 + ib];
    }
}

extern "C" void kernel_launch(void* const* d_in, const int* in_sizes, int n_in,
                              void* d_out, int out_size, void* d_ws, size_t ws_size,
                              hipStream_t stream) {
    const float* trip = (const float*)d_in[0];
    // d_in[1] = valid_len : unused by the reference computation
    const float* emb  = (const float*)d_in[2];
    const float* Wg   = (const float*)d_in[3];
    const float* bgp  = (const float*)d_in[4];
    const float* Wlp  = (const float*)d_in[5];
    const float* blp  = (const float*)d_in[6];
    float* out = (float*)d_out;

    // output = [trip (64*256*16=262144 floats) | out (64*4096*16=4194304 floats)]
    copy_trip_k<<<256, 256, 0, stream>>>((const float4*)trip, (float4*)out);
    recur_k<<<NBATCH, 512, 0, stream>>>(emb, Wg, bgp, Wlp, blp, out + 262144);
}